// Round 4
// baseline (359.191 us; speedup 1.0000x reference)
//
#include <hip/hip_runtime.h>
#include <hip/hip_bf16.h>

#define DID 512              // in_dim (K)
#define NV  512              // n_vars (tokens per batch)
#define NB  64               // batch
#define OD  720              // out_dim
#define OPAD 768             // out_dim padded to 128-multiple
#define NE  8                // experts
#define NTOK (NB * NV)       // 32768 tokens
#define MAXTILE 512

typedef short  bf16x8 __attribute__((ext_vector_type(8)));
typedef float  f32x4  __attribute__((ext_vector_type(4)));

// ---- workspace offsets (bytes) ----
#define XT_OFF    0u          // bf16 [B][V][D]          33,554,432
#define WB_OFF    33554432u   // bf16 [E][OPAD][D]        6,291,456
#define PID_OFF   39845888u   // int  [NTOK]
#define C1D_OFF   39976960u   // f32  [NTOK]
#define C2D_OFF   40108032u   // f32  [NTOK]
#define TL_OFF    40239104u   // int  [NTOK]
#define CL1_OFF   40370176u   // f32  [NTOK]
#define CL2_OFF   40501248u   // f32  [NTOK]
#define BCNT_OFF  40632320u   // int[64]  (bfill immediately after)
#define BFILL_OFF 40632576u   // int[64]
#define BOFF_OFF  40632832u   // int[64]
#define TPID_OFF  40633088u   // int[MAXTILE]
#define TT0_OFF   40635136u   // int[MAXTILE]
#define TEND_OFF  40637184u   // int[MAXTILE]
#define NT_OFF    40639232u   // int[1]
#define SCR_OFF   40639488u   // bf16 [NTOK][OD]         47,185,920
#define SCR_END   87825408u

static __device__ __forceinline__ ushort f2bf(float f) {
  unsigned u = __float_as_uint(f);
  unsigned r = (u + 0x7fffu + ((u >> 16) & 1u)) >> 16;   // RNE
  return (ushort)r;
}
static __device__ __forceinline__ float bf2f(ushort u) {
  return __uint_as_float(((unsigned)u) << 16);
}
static __device__ __forceinline__ void async16(const ushort* g, ushort* l) {
  __builtin_amdgcn_global_load_lds((__attribute__((address_space(1))) void*)(g),
                                   (__attribute__((address_space(3))) void*)(l),
                                   16, 0, 0);
}

// ---------------------------------------------------------------------------
// k_prep: fused  (a) x [B][D][V] fp32 -> XT [B][V][D] bf16   (z < 64)
//                (b) We -> WB bf16 padded                     (z >= 64)
//                (c) zero bcnt+bfill (one block)
// grid (16,16,72) x 256
// ---------------------------------------------------------------------------
__global__ __launch_bounds__(256) void k_prep(const float* __restrict__ x,
                                              ushort* __restrict__ xt,
                                              const float* __restrict__ We,
                                              ushort* __restrict__ wb,
                                              int* __restrict__ bcnt) {
  const int tid = threadIdx.x;
  if (blockIdx.z < 64) {
    if (blockIdx.z == 0 && blockIdx.x == 0 && blockIdx.y == 0 && tid < 128)
      bcnt[tid] = 0;                            // bcnt[64] + bfill[64]
    __shared__ float s[32][33];
    const int b  = blockIdx.z;
    const int v0 = blockIdx.x * 32;
    const int d0 = blockIdx.y * 32;
    const int tx = tid & 31;
    const int ty = tid >> 5;
    const float* xp = x + ((size_t)b * DID + d0 + ty) * NV + v0 + tx;
#pragma unroll
    for (int i = 0; i < 4; ++i) s[ty + i * 8][tx] = xp[(size_t)i * 8 * NV];
    __syncthreads();
#pragma unroll
    for (int i = 0; i < 4; ++i) {
      int vl = ty + i * 8;
      xt[((size_t)b * NV + v0 + vl) * DID + d0 + tx] = f2bf(s[tx][vl]);
    }
  } else {
    const int e = blockIdx.z - 64;
    int i = (blockIdx.y * 16 + blockIdx.x) * 256 + tid;   // 65536 threads
    for (; i < OPAD * DID; i += 65536) {
      const int o = i >> 9;
      ushort val = 0;
      if (o < OD) val = f2bf(We[(size_t)e * OD * DID + i]);
      wb[(size_t)e * OPAD * DID + i] = val;
    }
  }
}

// ---------------------------------------------------------------------------
// Gating (fp32 exact, must match reference top-k selection)
// ---------------------------------------------------------------------------
__global__ __launch_bounds__(256) void k_gate(const float* __restrict__ x,
                                              const float* __restrict__ Wg,
                                              int* __restrict__ pairid,
                                              float* __restrict__ c1d,
                                              float* __restrict__ c2d,
                                              int* __restrict__ bcnt) {
  __shared__ float wg[NE * DID];
  __shared__ int cnt64[64];
  const int tid = threadIdx.x;
  for (int i = tid; i < NE * DID; i += 256) wg[i] = Wg[i];
  if (tid < 64) cnt64[tid] = 0;
  __syncthreads();

  const int b = blockIdx.y;
  const int v = blockIdx.x * 256 + tid;
  const float* xp = x + (size_t)b * DID * NV + v;

  float acc[NE];
#pragma unroll
  for (int e = 0; e < NE; ++e) acc[e] = 0.f;
  for (int d = 0; d < DID; d += 4) {
    float x0 = xp[(size_t)(d + 0) * NV];
    float x1 = xp[(size_t)(d + 1) * NV];
    float x2 = xp[(size_t)(d + 2) * NV];
    float x3 = xp[(size_t)(d + 3) * NV];
#pragma unroll
    for (int e = 0; e < NE; ++e) {
      float4 w4 = *(const float4*)&wg[e * DID + d];
      acc[e] += x0 * w4.x + x1 * w4.y + x2 * w4.z + x3 * w4.w;
    }
  }
  float mx = acc[0];
#pragma unroll
  for (int e = 1; e < NE; ++e) mx = fmaxf(mx, acc[e]);
  float sum = 0.f;
#pragma unroll
  for (int e = 0; e < NE; ++e) { acc[e] = __expf(acc[e] - mx); sum += acc[e]; }
  const float inv = 1.f / sum;

  int i1 = 0; float g1 = acc[0];
#pragma unroll
  for (int e = 1; e < NE; ++e) if (acc[e] > g1) { g1 = acc[e]; i1 = e; }
  int i2 = -1; float g2 = -1.f;
#pragma unroll
  for (int e = 0; e < NE; ++e) if (e != i1 && acc[e] > g2) { g2 = acc[e]; i2 = e; }
  g1 *= inv; g2 *= inv;

  int ea, eb; float ca, cb;
  if (i1 < i2) { ea = i1; eb = i2; ca = g1; cb = g2; }
  else         { ea = i2; eb = i1; ca = g2; cb = g1; }
  const int pid = ea * 8 + eb;
  const int t = b * NV + v;
  pairid[t] = pid; c1d[t] = ca; c2d[t] = cb;
  atomicAdd(&cnt64[pid], 1);
  __syncthreads();
  if (tid < 64 && cnt64[tid]) atomicAdd(&bcnt[tid], cnt64[tid]);
}

// ---------------------------------------------------------------------------
// Parallel prefix over 64 buckets (one wave) + tile table
// ---------------------------------------------------------------------------
__global__ void k_prefix(const int* __restrict__ bcnt, int* __restrict__ boffs,
                         int* __restrict__ tpid, int* __restrict__ tt0,
                         int* __restrict__ tend, int* __restrict__ ntp) {
  const int p = threadIdx.x;        // 64 lanes
  const int c = bcnt[p];
  int inc = c;
#pragma unroll
  for (int d = 1; d < 64; d <<= 1) {
    int n = __shfl_up(inc, d, 64);
    if (p >= d) inc += n;
  }
  const int off = inc - c;
  boffs[p] = off;
  const int tc = (c + 127) >> 7;
  int inct = tc;
#pragma unroll
  for (int d = 1; d < 64; d <<= 1) {
    int n = __shfl_up(inct, d, 64);
    if (p >= d) inct += n;
  }
  const int tb = inct - tc;
  for (int i = 0; i < tc; ++i) {
    tpid[tb + i] = p; tt0[tb + i] = off + i * 128; tend[tb + i] = off + c;
  }
  if (p == 63) ntp[0] = inct;
}

// ---------------------------------------------------------------------------
// Scatter tokens into packed per-bucket lists
// ---------------------------------------------------------------------------
__global__ __launch_bounds__(256) void k_scatter(const int* __restrict__ pairid,
                                                 const float* __restrict__ c1d,
                                                 const float* __restrict__ c2d,
                                                 const int* __restrict__ boffs,
                                                 int* __restrict__ bfill,
                                                 int* __restrict__ tlist,
                                                 float* __restrict__ cl1,
                                                 float* __restrict__ cl2) {
  __shared__ int cnt64[64], base64[64];
  const int tid = threadIdx.x;
  if (tid < 64) cnt64[tid] = 0;
  __syncthreads();
  const int t = blockIdx.x * 256 + tid;
  const int pid = pairid[t];
  const int p = atomicAdd(&cnt64[pid], 1);
  __syncthreads();
  if (tid < 64) base64[tid] = cnt64[tid] ? atomicAdd(&bfill[tid], cnt64[tid]) : 0;
  __syncthreads();
  const int slot = boffs[pid] + base64[pid] + p;
  tlist[slot] = t; cl1[slot] = c1d[t]; cl2[slot] = c2d[t];
}

// ---------------------------------------------------------------------------
// Pair-bucket GEMM, fragment-order LDS staging (conflict-free):
// each staged block = 16 rows x 32 k, lane l holds row (l&15), k-chunk (l>>4)
// -> MFMA frag read is ds_read_b128 at base + lane*16.
// grid (6 o-tiles fastest, 320 token-tiles) for xt L2/L3 temporal reuse.
// ---------------------------------------------------------------------------
__global__ __launch_bounds__(256, 2) void k_gemm(
    const ushort* __restrict__ xt, const ushort* __restrict__ wb,
    const float* __restrict__ be, const int* __restrict__ tlist,
    const float* __restrict__ cl1, const float* __restrict__ cl2,
    const int* __restrict__ tpid, const int* __restrict__ tt0,
    const int* __restrict__ tendarr, const int* __restrict__ ntp,
    ushort* __restrict__ scratch, float* __restrict__ out, int mode) {
  const int tile = blockIdx.y;
  if (tile >= ntp[0]) return;
  const int pid  = tpid[tile];
  const int t0   = tt0[tile];
  const int tend = tendarr[tile];
  const int e1 = pid >> 3, e2 = pid & 7;
  const int o0 = blockIdx.x * 128;

  // [buf][block(8)][1024B]: block b = rows 16b..16b+15, 32 k
  __shared__ __align__(16) ushort As[2][4096];
  __shared__ __align__(16) ushort Bs[2][4096];

  const int tid  = threadIdx.x;
  const int lane = tid & 63;
  const int w    = tid >> 6;
  const int m16  = lane & 15;
  const int ch   = lane >> 4;          // k-chunk 0..3

  // wave w stages blocks 2w and 2w+1 of both A and B
  const int rA0 = 2 * w * 16 + m16;    // row within 128-tile
  const int sl0 = t0 + rA0, sl1 = sl0 + 16;
  const int tk0 = (sl0 < tend) ? tlist[sl0] : 0;
  const int tk1 = (sl1 < tend) ? tlist[sl1] : 0;

  const size_t eStride = (size_t)OPAD * DID;
  const int    aoff    = (o0 + rA0) * DID + ch * 8;       // A offset within expert
  const ushort* gb0 = xt + (size_t)tk0 * DID + ch * 8;
  const ushort* gb1 = xt + (size_t)tk1 * DID + ch * 8;

  const int dst0 = 2 * w * 512 + lane * 8;       // ushort index in [buf]
  const int dst1 = dst0 + 512;

  const int m    = lane & 15;
  const int quad = lane >> 4;
  const int wo   = (w >> 1) * 64;                // wave o-offset
  const int wt   = (w & 1) * 64;                 // wave token-offset
  const int fa   = (w >> 1) * 4;                 // A frag block base
  const int fb   = (w & 1) * 4;                  // B frag block base

  f32x4 acc[4][4];
#pragma unroll
  for (int i = 0; i < 4; ++i)
#pragma unroll
    for (int j = 0; j < 4; ++j) acc[i][j] = (f32x4){0.f, 0.f, 0.f, 0.f};

  // prologue: stage kk=0 (expert e1) into buffer 0
  {
    const ushort* wA = wb + (size_t)e1 * eStride + aoff;
    async16(wA, &As[0][dst0]);
    async16(wA + 16 * DID, &As[0][dst1]);
    async16(gb0, &Bs[0][dst0]);
    async16(gb1, &Bs[0][dst1]);
  }

  for (int kk = 0; kk < 32; ++kk) {
    __syncthreads();   // stage kk visible; frag reads of kk-1 done

    if (kk == 16) {
      // fold expert-1: acc = (acc + be1[o]) * (c1/c2)
      float ratio[4];
#pragma unroll
      for (int j = 0; j < 4; ++j) {
        const int sl = t0 + wt + j * 16 + m;
        const bool g = sl < tend;
        const float cc1 = g ? cl1[sl] : 0.f;
        const float cc2 = g ? cl2[sl] : 1.f;
        ratio[j] = cc1 / cc2;
      }
      const float* be1p = be + e1 * OD;
#pragma unroll
      for (int i = 0; i < 4; ++i) {
        const int ob = o0 + wo + i * 16 + quad * 4;
        float b0 = 0, b1 = 0, b2 = 0, b3 = 0;
        if (ob < OD) { b0 = be1p[ob]; b1 = be1p[ob + 1]; b2 = be1p[ob + 2]; b3 = be1p[ob + 3]; }
#pragma unroll
        for (int j = 0; j < 4; ++j) {
          acc[i][j][0] = (acc[i][j][0] + b0) * ratio[j];
          acc[i][j][1] = (acc[i][j][1] + b1) * ratio[j];
          acc[i][j][2] = (acc[i][j][2] + b2) * ratio[j];
          acc[i][j][3] = (acc[i][j][3] + b3) * ratio[j];
        }
      }
    }

    // prefetch stage kk+1 into the other buffer
    const int nk = kk + 1;
    if (nk < 32) {
      const int nb = nk & 1;
      const int eA = (nk < 16) ? e1 : e2;
      const int k0 = (nk & 15) * 32;
      const ushort* wA = wb + (size_t)eA * eStride + aoff + k0;
      async16(wA, &As[nb][dst0]);
      async16(wA + 16 * DID, &As[nb][dst1]);
      async16(gb0 + k0, &Bs[nb][dst0]);
      async16(gb1 + k0, &Bs[nb][dst1]);
    }

    const int cb = kk & 1;
    bf16x8 af[4], bfr[4];
#pragma unroll
    for (int i = 0; i < 4; ++i)
      af[i] = *(const bf16x8*)(&As[cb][(fa + i) * 512 + lane * 8]);
#pragma unroll
    for (int j = 0; j < 4; ++j)
      bfr[j] = *(const bf16x8*)(&Bs[cb][(fb + j) * 512 + lane * 8]);
#pragma unroll
    for (int i = 0; i < 4; ++i)
#pragma unroll
      for (int j = 0; j < 4; ++j)
        acc[i][j] = __builtin_amdgcn_mfma_f32_16x16x32_bf16(af[i], bfr[j],
                                                            acc[i][j], 0, 0, 0);
  }

  // epilogue: val = c2 * (acc + be2[o])
  float c2v[4]; int tokv[4]; bool gv[4];
#pragma unroll
  for (int j = 0; j < 4; ++j) {
    const int sl = t0 + wt + j * 16 + m;
    gv[j] = sl < tend;
    c2v[j]  = gv[j] ? cl2[sl] : 0.f;
    tokv[j] = gv[j] ? tlist[sl] : 0;
  }
  const float* be2p = be + e2 * OD;
#pragma unroll
  for (int i = 0; i < 4; ++i) {
    const int ob = o0 + wo + i * 16 + quad * 4;
    if (ob < OD) {
      const float b0 = be2p[ob], b1 = be2p[ob + 1], b2 = be2p[ob + 2], b3 = be2p[ob + 3];
#pragma unroll
      for (int j = 0; j < 4; ++j) {
        if (gv[j]) {
          const float v0 = c2v[j] * (acc[i][j][0] + b0);
          const float v1 = c2v[j] * (acc[i][j][1] + b1);
          const float v2 = c2v[j] * (acc[i][j][2] + b2);
          const float v3 = c2v[j] * (acc[i][j][3] + b3);
          if (mode == 0) {
            ushort4 pk = make_ushort4(f2bf(v0), f2bf(v1), f2bf(v2), f2bf(v3));
            *(ushort4*)(scratch + (size_t)tokv[j] * OD + ob) = pk;
          } else {
            const int bb = tokv[j] >> 9, vv = tokv[j] & 511;
            float* op = out + ((size_t)bb * OD + ob) * NV + vv;
            op[0] = v0; op[(size_t)NV] = v1; op[2 * (size_t)NV] = v2; op[3 * (size_t)NV] = v3;
          }
        }
      }
    }
  }
}

// ---------------------------------------------------------------------------
// scratch bf16 [NTOK][OD] -> out fp32 [B][OD][V]
// ---------------------------------------------------------------------------
__global__ __launch_bounds__(256) void k_combine(const ushort* __restrict__ scratch,
                                                 float* __restrict__ out) {
  __shared__ ushort s[64][68];
  const int v0 = blockIdx.x * 64;
  const int o0 = blockIdx.y * 64;
  const int b  = blockIdx.z;
  const int tid = threadIdx.x;
#pragma unroll
  for (int it = 0; it < 2; ++it) {
    const int c = it * 256 + tid;
    const int row = c >> 3, cg = c & 7;
    const int o = o0 + cg * 8;
    if (o + 8 <= OD) {
      const ushort* src = scratch + ((size_t)(b * NV + v0 + row)) * OD + o;
      ushort4 ua = *(const ushort4*)(src);
      ushort4 ub = *(const ushort4*)(src + 4);
      *(ushort4*)&s[row][cg * 8] = ua;
      *(ushort4*)&s[row][cg * 8 + 4] = ub;
    }
  }
  __syncthreads();
  const int vv = tid & 63;
  const int og = tid >> 6;
#pragma unroll
  for (int oi = 0; oi < 8; ++oi) {
    const int ol = (og * 8 + oi) * 2;
    const int o = o0 + ol;
    if (o < OD) {
      ushort2 u = *(const ushort2*)&s[vv][ol];
      float* op = out + ((size_t)b * OD + o) * NV + v0 + vv;
      op[0]  = bf2f(u.x);
      op[NV] = bf2f(u.y);
    }
  }
}

// ---------------------------------------------------------------------------
extern "C" void kernel_launch(void* const* d_in, const int* in_sizes, int n_in,
                              void* d_out, int out_size, void* d_ws, size_t ws_size,
                              hipStream_t stream) {
  const float* x  = (const float*)d_in[0];
  const float* Wg = (const float*)d_in[1];
  const float* We = (const float*)d_in[2];
  const float* be = (const float*)d_in[3];
  float* out = (float*)d_out;

  char* ws = (char*)d_ws;
  ushort* xt     = (ushort*)(ws + XT_OFF);
  ushort* wb     = (ushort*)(ws + WB_OFF);
  int*    pairid = (int*)   (ws + PID_OFF);
  float*  c1d    = (float*) (ws + C1D_OFF);
  float*  c2d    = (float*) (ws + C2D_OFF);
  int*    tlist  = (int*)   (ws + TL_OFF);
  float*  cl1    = (float*) (ws + CL1_OFF);
  float*  cl2    = (float*) (ws + CL2_OFF);
  int*    bcnt   = (int*)   (ws + BCNT_OFF);
  int*    bfill  = (int*)   (ws + BFILL_OFF);
  int*    boffs  = (int*)   (ws + BOFF_OFF);
  int*    tpid   = (int*)   (ws + TPID_OFF);
  int*    tt0    = (int*)   (ws + TT0_OFF);
  int*    tend   = (int*)   (ws + TEND_OFF);
  int*    ntp    = (int*)   (ws + NT_OFF);
  ushort* scratch= (ushort*)(ws + SCR_OFF);

  const int mode = (ws_size >= (size_t)SCR_END) ? 0 : 1;

  k_prep<<<dim3(16, 16, 72), 256, 0, stream>>>(x, xt, We, wb, bcnt);
  k_gate<<<dim3(NV / 256, NB), 256, 0, stream>>>(x, Wg, pairid, c1d, c2d, bcnt);
  k_prefix<<<1, 64, 0, stream>>>(bcnt, boffs, tpid, tt0, tend, ntp);
  k_scatter<<<NTOK / 256, 256, 0, stream>>>(pairid, c1d, c2d, boffs, bfill,
                                            tlist, cl1, cl2);
  k_gemm<<<dim3(OPAD / 128, 320), 256, 0, stream>>>(xt, wb, be, tlist, cl1, cl2,
                                                    tpid, tt0, tend, ntp,
                                                    scratch, out, mode);
  if (mode == 0)
    k_combine<<<dim3(NV / 64, (OD + 63) / 64, NB), 256, 0, stream>>>(scratch, out);
}